// Round 8
// baseline (218.391 us; speedup 1.0000x reference)
//
#include <hip/hip_runtime.h>

#define HH 512
#define WW 512
#define ROWS 8
#define W4 (WW/4)          // 128 words per gray row
#define CH_STRIDE (HH*WW)
#define IMG_STRIDE (3*HH*WW)
#define SPB 4              // strips per block (software pipeline depth)
#define NQ (HH/(ROWS*SPB)) // 16 quarters per image

// quantize one channel value: floor(clip(v*255, 0, 255))
__device__ __forceinline__ float quant(float v) {
    return floorf(fminf(fmaxf(v * 255.0f, 0.0f), 255.0f));
}

// pack 4 gray pixels (rounded, cv2 RGB2GRAY weights) into one word.
// KEEP the arithmetic BIT-IDENTICAL to the validated R1/R2/R3 expression.
__device__ __forceinline__ unsigned pack_gray(float4 r, float4 g, float4 b) {
    const unsigned o0 = (unsigned)rintf(0.299f * quant(r.x) + 0.587f * quant(g.x) + 0.114f * quant(b.x));
    const unsigned o1 = (unsigned)rintf(0.299f * quant(r.y) + 0.587f * quant(g.y) + 0.114f * quant(b.y));
    const unsigned o2 = (unsigned)rintf(0.299f * quant(r.z) + 0.587f * quant(g.z) + 0.114f * quant(b.z));
    const unsigned o3 = (unsigned)rintf(0.299f * quant(r.w) + 0.587f * quant(g.w) + 0.114f * quant(b.w));
    return o0 | (o1 << 8) | (o2 << 16) | (o3 << 24);
}

// 4 rounded sobel-avg values (exact integer path) for word w4v of LDS row lr
__device__ __forceinline__ void sobel4(const unsigned* __restrict__ g, int lr, int w4v, int out[4]) {
    const unsigned c0 = g[(lr - 1) * W4 + w4v];
    const unsigned c1 = g[lr * W4 + w4v];
    const unsigned c2 = g[(lr + 1) * W4 + w4v];
    const unsigned lw = g[lr * W4 + (w4v == 0 ? 0 : w4v - 1)];
    const unsigned rw = g[lr * W4 + (w4v == W4 - 1 ? W4 - 1 : w4v + 1)];

    int gx[6];
    // reflect101 at image edges: left neighbor of px0 is px1; right of px511 is px510
    gx[0] = (w4v == 0) ? (int)((c1 >> 8) & 255u) : (int)(lw >> 24);
    gx[1] = (int)(c1 & 255u);
    gx[2] = (int)((c1 >> 8) & 255u);
    gx[3] = (int)((c1 >> 16) & 255u);
    gx[4] = (int)(c1 >> 24);
    gx[5] = (w4v == W4 - 1) ? (int)((c1 >> 16) & 255u) : (int)(rw & 255u);

#pragma unroll
    for (int j = 0; j < 4; ++j) {
        const int sx = __builtin_abs(gx[j + 2] - gx[j]);
        const int sy = __builtin_abs((int)((c2 >> (8 * j)) & 255u) - (int)((c0 >> (8 * j)) & 255u));
        const int s = sx + sy;
        // round-half-even of s/2
        out[j] = (s >> 1) + ((s & 1) & ((s >> 1) & 1));
    }
}

// __launch_bounds__(256,2): allow up to ~256 VGPR so the 30-load prefetch
// batch stays in registers/in flight (R3's VGPR=64 showed the default
// heuristic chops the batch).
__global__ __launch_bounds__(256, 2) void sobel_loss_kernel(
    const float* __restrict__ pred, const float* __restrict__ gt_,
    float* __restrict__ out)
{
    __shared__ unsigned gp[(ROWS + 2) * W4];
    __shared__ unsigned gq[(ROWS + 2) * W4];
    __shared__ int red[4];

    const int b = blockIdx.x >> 4;          // / NQ
    const int q = blockIdx.x & (NQ - 1);    // quarter within image

    const float* P = pred + (size_t)b * IMG_STRIDE;
    const float* T = gt_  + (size_t)b * IMG_STRIDE;

    const int wq  = threadIdx.x & (W4 - 1); // word column 0..127
    const int lrb = threadIdx.x >> 7;       // row-group base: 0 or 1

    float4 vp[5][3], vt[5][3];
    int acc = 0;

    // row byte-offset for row-group k of strip s (BORDER_REFLECT_101)
    auto rowoff = [&](int s, int k) {
        int gr = (q * SPB + s) * ROWS - 1 + lrb + 2 * k;
        gr = (gr < 0) ? 1 : ((gr > HH - 1) ? 2 * (HH - 1) - gr : gr);
        return gr * WW;
    };

    // ---- prologue: issue strip-0 loads ----
#pragma unroll
    for (int k = 0; k < 5; ++k) {
        const int go = rowoff(0, k);
#pragma unroll
        for (int c = 0; c < 3; ++c)
            vp[k][c] = reinterpret_cast<const float4*>(P + c * CH_STRIDE + go)[wq];
    }
#pragma unroll
    for (int k = 0; k < 5; ++k) {
        const int go = rowoff(0, k);
#pragma unroll
        for (int c = 0; c < 3; ++c)
            vt[k][c] = reinterpret_cast<const float4*>(T + c * CH_STRIDE + go)[wq];
    }

    // ---- pipelined strip loop ----
#pragma unroll
    for (int s = 0; s < SPB; ++s) {
        unsigned pwp[5], pwt[5];

        // pack P (waits only on P loads), then immediately reuse vp for prefetch
#pragma unroll
        for (int k = 0; k < 5; ++k) pwp[k] = pack_gray(vp[k][0], vp[k][1], vp[k][2]);
        if (s < SPB - 1) {
#pragma unroll
            for (int k = 0; k < 5; ++k) {
                const int go = rowoff(s + 1, k);
#pragma unroll
                for (int c = 0; c < 3; ++c)
                    vp[k][c] = reinterpret_cast<const float4*>(P + c * CH_STRIDE + go)[wq];
            }
        }
        // pack T (next-P loads in flight), then reuse vt for prefetch
#pragma unroll
        for (int k = 0; k < 5; ++k) pwt[k] = pack_gray(vt[k][0], vt[k][1], vt[k][2]);
        if (s < SPB - 1) {
#pragma unroll
            for (int k = 0; k < 5; ++k) {
                const int go = rowoff(s + 1, k);
#pragma unroll
                for (int c = 0; c < 3; ++c)
                    vt[k][c] = reinterpret_cast<const float4*>(T + c * CH_STRIDE + go)[wq];
            }
        }

        // stage packed gray to LDS
#pragma unroll
        for (int k = 0; k < 5; ++k) {
            const int di = (lrb + 2 * k) * W4 + wq;
            gp[di] = pwp[k];
            gq[di] = pwt[k];
        }

        // barrier WITHOUT draining vmcnt: prefetch loads stay in flight.
        // LDS ops are memory ops, so the "memory" clobber orders them (cf. rule 18).
        asm volatile("s_waitcnt lgkmcnt(0)" ::: "memory");
        __builtin_amdgcn_s_barrier();

        // ---- integer sobel + |diff| accumulate (exact) ----
#pragma unroll
        for (int j = 0; j < 4; ++j) {
            const int lr = lrb + 2 * j + 1;   // LDS row 1..8
            int sp[4], st[4];
            sobel4(gp, lr, wq, sp);
            sobel4(gq, lr, wq, st);
#pragma unroll
            for (int t2 = 0; t2 < 4; ++t2)
                acc += __builtin_abs(sp[t2] - st[t2]);
        }

        // all ds_reads returned before anyone overwrites the tile next iter
        asm volatile("s_waitcnt lgkmcnt(0)" ::: "memory");
        __builtin_amdgcn_s_barrier();
    }

    // ---- reduce: wave shuffle, then cross-wave ----
    for (int off = 32; off > 0; off >>= 1)
        acc += __shfl_down(acc, off, 64);

    const int lane = threadIdx.x & 63;
    const int wid  = threadIdx.x >> 6;
    if (lane == 0) red[wid] = acc;
    __syncthreads();
    if (threadIdx.x == 0) {
        const int s = red[0] + red[1] + red[2] + red[3];
        // mean over 32*512*512 elements, then /255
        atomicAdd(out, (float)s * (1.0f / (255.0f * 32.0f * 512.0f * 512.0f)));
    }
}

extern "C" void kernel_launch(void* const* d_in, const int* in_sizes, int n_in,
                              void* d_out, int out_size, void* d_ws, size_t ws_size,
                              hipStream_t stream) {
    const float* y_pred = (const float*)d_in[0];
    const float* y_true = (const float*)d_in[1];
    float* out = (float*)d_out;

    // harness re-poisons d_out with 0xAA before every timed launch
    hipMemsetAsync(out, 0, out_size * sizeof(float), stream);

    const int nblk = 32 * NQ;   // 512 blocks: one per (batch, 4-strip quarter)
    sobel_loss_kernel<<<nblk, 256, 0, stream>>>(y_pred, y_true, out);
}